// Round 3
// baseline (169.266 us; speedup 1.0000x reference)
//
#include <hip/hip_runtime.h>

#define THREADS 512
#define HW 16384        // H*W per (b,c) row
#define K_SEL 8192u     // k = 0.5 * H * W
#define NB1 2048        // pass-1 bins: abs bits [30:20]
#define NB2 1024        // pass-2/3 bins: 10 bits each
#define VPT 8           // uint4 per thread per row (THREADS*VPT*4 == HW)
#define RPB 8           // rows per block

// All-wave redundant bin search: every wave computes the identical result in
// registers (LDS same-address reads broadcast; no cross-wave sync needed).
// hist bins ascend in value; returns the bin containing the kRem-th LARGEST
// element and the residual rank within that bin.
template <int NBINS>
__device__ __forceinline__ void find_bin(const unsigned* __restrict__ hist,
                                         unsigned kRem, unsigned& bin, unsigned& krem) {
  constexpr int bpl = NBINS >> 6;             // bins per lane (contiguous chunk)
  const int lane = (int)(threadIdx.x & 63);
  const int base = lane * bpl;
  // Bank-rotated chunk sum: conflict-free.
  unsigned s = 0;
#pragma unroll
  for (int j = 0; j < bpl; ++j) s += hist[base + ((j + lane) & (bpl - 1))];
  // Inclusive suffix sum across lanes (higher lanes = larger values).
  unsigned suf = s;
#pragma unroll
  for (int off = 1; off < 64; off <<= 1) {
    unsigned w = __shfl_down(suf, off);
    if (lane + off < 64) suf += w;
  }
  const unsigned cumAbove = suf - s;
  const bool hit = (cumAbove < kRem) && (kRem <= suf);
  const unsigned long long m = __ballot(hit);
  const int tl = (int)__builtin_ctzll(m);     // unique target lane
  const unsigned cumTl = __shfl(cumAbove, tl);
  // Parallel sub-chunk suffix scan: groups of bpl lanes redundantly scan the
  // target chunk (same-address LDS reads -> broadcast, free).
  const int j = lane & (bpl - 1);
  const unsigned h = hist[tl * bpl + j];
  unsigned sufc = h;
#pragma unroll
  for (int off = 1; off < 32; off <<= 1) {
    if (off < bpl) {
      unsigned w = __shfl_down(sufc, off);
      if (j + off < bpl) sufc += w;
    }
  }
  const unsigned cumW = sufc - h;             // within-chunk count above bin j
  const bool hit2 = ((cumTl + cumW) < kRem) && (kRem <= cumTl + cumW + h);
  const unsigned long long m2 = __ballot(hit2);
  const int jl = (int)__builtin_ctzll(m2) & (bpl - 1);
  bin = (unsigned)(tl * bpl + jl);
  krem = kRem - cumTl - __shfl(cumW, jl);
}

__device__ __forceinline__ void load_row(uint4 (&v)[VPT], const uint4* __restrict__ src, int t) {
#pragma unroll
  for (int i = 0; i < VPT; ++i) v[i] = src[i * THREADS + t];
}

// Full select + masked store for one row held in registers.
// 3 barriers/row; hist zeroing folded into disjoint-buffer phases:
//   P1 (atomics h1) also zeros h2;  P2 (h2) zeros h3;  P3 (h3) zeros h1.
__device__ __forceinline__ void process_row(uint4 (&v)[VPT],
                                            unsigned* __restrict__ h1,
                                            unsigned* __restrict__ h2,
                                            unsigned* __restrict__ h3,
                                            uint4* __restrict__ dst, int t) {
  // P1: bits [30:20] histogram (h1 pre-zeroed by prologue / previous P3).
#pragma unroll
  for (int i = 0; i < VPT; ++i) {
    atomicAdd(&h1[(v[i].x & 0x7fffffffu) >> 20], 1u);
    atomicAdd(&h1[(v[i].y & 0x7fffffffu) >> 20], 1u);
    atomicAdd(&h1[(v[i].z & 0x7fffffffu) >> 20], 1u);
    atomicAdd(&h1[(v[i].w & 0x7fffffffu) >> 20], 1u);
  }
#pragma unroll
  for (int i = t; i < NB2; i += THREADS) h2[i] = 0;   // dead since prev find2
  __syncthreads();
  unsigned T1, kRem;
  find_bin<NB1>(h1, K_SEL, T1, kRem);

  // P2: among top-digit==T1, histogram bits [19:10].
#pragma unroll
  for (int i = 0; i < VPT; ++i) {
    unsigned a;
    a = v[i].x & 0x7fffffffu; if ((a >> 20) == T1) atomicAdd(&h2[(a >> 10) & (NB2 - 1)], 1u);
    a = v[i].y & 0x7fffffffu; if ((a >> 20) == T1) atomicAdd(&h2[(a >> 10) & (NB2 - 1)], 1u);
    a = v[i].z & 0x7fffffffu; if ((a >> 20) == T1) atomicAdd(&h2[(a >> 10) & (NB2 - 1)], 1u);
    a = v[i].w & 0x7fffffffu; if ((a >> 20) == T1) atomicAdd(&h2[(a >> 10) & (NB2 - 1)], 1u);
  }
#pragma unroll
  for (int i = t; i < NB2; i += THREADS) h3[i] = 0;   // dead since prev find3
  __syncthreads();
  unsigned b2;
  find_bin<NB2>(h2, kRem, b2, kRem);
  const unsigned pref2 = (T1 << 10) | b2;

  // P3: among bits[30:10]==pref2, histogram bits [9:0].
#pragma unroll
  for (int i = 0; i < VPT; ++i) {
    unsigned a;
    a = v[i].x & 0x7fffffffu; if ((a >> 10) == pref2) atomicAdd(&h3[a & (NB2 - 1)], 1u);
    a = v[i].y & 0x7fffffffu; if ((a >> 10) == pref2) atomicAdd(&h3[a & (NB2 - 1)], 1u);
    a = v[i].z & 0x7fffffffu; if ((a >> 10) == pref2) atomicAdd(&h3[a & (NB2 - 1)], 1u);
    a = v[i].w & 0x7fffffffu; if ((a >> 10) == pref2) atomicAdd(&h3[a & (NB2 - 1)], 1u);
  }
#pragma unroll
  for (int i = t; i < NB1; i += THREADS) h1[i] = 0;   // dead since this find1
  __syncthreads();
  unsigned b3, kDummy;
  find_bin<NB2>(h3, kRem, b3, kDummy);
  const unsigned thr = (pref2 << 10) | b3;            // exact k-th largest |x| bits

  // Masked store (>= keeps ties, same as reference).
#pragma unroll
  for (int i = 0; i < VPT; ++i) {
    uint4 w = v[i];
    w.x = ((w.x & 0x7fffffffu) >= thr) ? w.x : 0u;
    w.y = ((w.y & 0x7fffffffu) >= thr) ? w.y : 0u;
    w.z = ((w.z & 0x7fffffffu) >= thr) ? w.z : 0u;
    w.w = ((w.w & 0x7fffffffu) >= thr) ? w.w : 0u;
    dst[i * THREADS + t] = w;
  }
}

extern "C" __global__ __launch_bounds__(THREADS, 4)
void sparsify_topk_kernel(const float* __restrict__ x, float* __restrict__ out) {
  __shared__ unsigned h1[NB1];
  __shared__ unsigned h2[NB2];
  __shared__ unsigned h3[NB2];

  const int t = (int)threadIdx.x;
  const size_t base = (size_t)blockIdx.x * RPB * (HW / 4);
  const uint4* src = (const uint4*)x + base;
  uint4*       dst = (uint4*)out + base;

  // Prologue: only h1 needs zeroing (h2/h3 zeroed inside row 0's P1/P2).
  for (int i = t; i < NB1; i += THREADS) h1[i] = 0;
  __syncthreads();

  // Two-row register ping-pong: row r+2's loads issue right after row r's
  // stores, so every compute phase has one row-load streaming underneath.
  uint4 vA[VPT], vB[VPT];
  load_row(vA, src + 0 * (HW / 4), t);
  load_row(vB, src + 1 * (HW / 4), t);

#pragma unroll
  for (int p = 0; p < RPB / 2; ++p) {
    const int r0 = 2 * p, r1 = 2 * p + 1;
    process_row(vA, h1, h2, h3, dst + r0 * (HW / 4), t);
    if (r0 + 2 < RPB) load_row(vA, src + (r0 + 2) * (HW / 4), t);
    process_row(vB, h1, h2, h3, dst + r1 * (HW / 4), t);
    if (r1 + 2 < RPB) load_row(vB, src + (r1 + 2) * (HW / 4), t);
  }
}

extern "C" void kernel_launch(void* const* d_in, const int* in_sizes, int n_in,
                              void* d_out, int out_size, void* d_ws, size_t ws_size,
                              hipStream_t stream) {
  (void)n_in; (void)d_ws; (void)ws_size; (void)out_size;
  const float* x = (const float*)d_in[0];
  float* out = (float*)d_out;
  const int rows = in_sizes[0] / HW;   // 4096
  const int blocks = rows / RPB;       // 512
  sparsify_topk_kernel<<<dim3(blocks), dim3(THREADS), 0, stream>>>(x, out);
}

// Round 4
// 143.883 us; speedup vs baseline: 1.1764x; 1.1764x over previous
//
#include <hip/hip_runtime.h>
#include <stdint.h>

#define THREADS 256
#define HW 16384        // H*W per (b,c) row
#define K_SEL 8192u     // k = 0.5 * H * W
#define NB1 2048        // pass-1: abs bits [30:20]
#define NB2 128         // pass-2: bits [19:13]
#define NB3 128         // pass-3: bits [12:6]
#define NB4 64          // pass-4: bits [5:0]
#define VPT 16          // uint4 per thread (64 floats); THREADS*VPT*4 == HW
#define RPB 8           // rows per block
#define LDS_WORDS (HW + NB1 + NB2 + NB3 + NB4)   // 18752 words = 75008 B

static_assert(THREADS * VPT * 4 == HW, "row tiling");

// Raw barrier that waits LDS ops only — does NOT drain vmcnt, so the async
// global->LDS DMA of the next row keeps flying across histogram phases.
__device__ __forceinline__ void lgk_barrier() {
  asm volatile("s_waitcnt lgkmcnt(0)" ::: "memory");
  __builtin_amdgcn_s_barrier();
}

// Issue one row (64 KB) global->LDS via async DMA. Per wave: 16 chunks of
// 1024 B (64 lanes x 16 B). LDS dest is wave-uniform base; HW adds lane*16.
__device__ __forceinline__ void dma_row(const unsigned* __restrict__ gsrc,
                                        unsigned* lds, int wid, int lane) {
#pragma unroll
  for (int i = 0; i < 16; ++i) {
    const int chunk = wid * 16 + i;
    __builtin_amdgcn_global_load_lds(
        (const __attribute__((address_space(1))) unsigned*)(gsrc + chunk * 256 + lane * 4),
        (__attribute__((address_space(3))) unsigned*)(lds + chunk * 256),
        16, 0, 0);
  }
}

// All-wave redundant bin search (results identical in every wave's registers;
// no broadcast, no extra barrier). Bins ascend in value; returns the bin
// holding the kRem-th LARGEST element and the residual rank within it.
template <int NBINS>
__device__ __forceinline__ void find_bin(const unsigned* __restrict__ hist,
                                         unsigned kRem, unsigned& bin, unsigned& krem) {
  constexpr int bpl = NBINS >> 6;             // bins per lane (>=1)
  const int lane = (int)(threadIdx.x & 63);
  const int base = lane * bpl;
  unsigned s = 0;
#pragma unroll
  for (int j = 0; j < bpl; ++j) s += hist[base + ((j + lane) & (bpl - 1))];
  unsigned suf = s;                            // inclusive suffix sum over lanes
#pragma unroll
  for (int off = 1; off < 64; off <<= 1) {
    unsigned w = __shfl_down(suf, off);
    if (lane + off < 64) suf += w;
  }
  const unsigned cumAbove = suf - s;
  const bool hit = (cumAbove < kRem) && (kRem <= suf);
  const unsigned long long m = __ballot(hit);
  const int tl = (int)__builtin_ctzll(m);
  const unsigned cumTl = __shfl(cumAbove, tl);
  // Within-chunk suffix scan, done redundantly by every bpl-lane group.
  const int j = (bpl > 1) ? (lane & (bpl - 1)) : 0;
  const unsigned h = hist[tl * bpl + j];
  unsigned sufc = h;
#pragma unroll
  for (int off = 1; off < 32; off <<= 1) {
    if (off < bpl) {
      unsigned w = __shfl_down(sufc, off);
      if (j + off < bpl) sufc += w;
    }
  }
  const unsigned cumW = sufc - h;
  const bool hit2 = ((cumTl + cumW) < kRem) && (kRem <= cumTl + cumW + h);
  const unsigned long long m2 = __ballot(hit2);
  const int jl = (bpl > 1) ? ((int)__builtin_ctzll(m2) & (bpl - 1)) : 0;
  bin = (unsigned)(tl * bpl + jl);
  krem = kRem - cumTl - __shfl(cumW, jl);
}

// 4-pass exact radix select on |x| bits (11+7+7+6) + masked store.
// Disjoint hist buffers; each phase zeros the NEXT pass's buffer (dead since
// its last find). 4 lgk-only barriers; vmcnt untouched.
__device__ __forceinline__ void process_row(const uint4 (&v)[VPT],
                                            unsigned* h1, unsigned* h2,
                                            unsigned* h3, unsigned* h4,
                                            uint4* __restrict__ dstRow, int t) {
  // P1: bits [30:20] -> h1 ; zero h2.
#pragma unroll
  for (int i = 0; i < VPT; ++i) {
    atomicAdd(&h1[(v[i].x & 0x7fffffffu) >> 20], 1u);
    atomicAdd(&h1[(v[i].y & 0x7fffffffu) >> 20], 1u);
    atomicAdd(&h1[(v[i].z & 0x7fffffffu) >> 20], 1u);
    atomicAdd(&h1[(v[i].w & 0x7fffffffu) >> 20], 1u);
  }
  if (t < NB2) h2[t] = 0;
  lgk_barrier();
  unsigned T1, kRem;
  find_bin<NB1>(h1, K_SEL, T1, kRem);

  // P2: among (a>>20)==T1, bits [19:13] -> h2 ; zero h3.
#pragma unroll
  for (int i = 0; i < VPT; ++i) {
    unsigned a;
    a = v[i].x & 0x7fffffffu; if ((a >> 20) == T1) atomicAdd(&h2[(a >> 13) & (NB2 - 1)], 1u);
    a = v[i].y & 0x7fffffffu; if ((a >> 20) == T1) atomicAdd(&h2[(a >> 13) & (NB2 - 1)], 1u);
    a = v[i].z & 0x7fffffffu; if ((a >> 20) == T1) atomicAdd(&h2[(a >> 13) & (NB2 - 1)], 1u);
    a = v[i].w & 0x7fffffffu; if ((a >> 20) == T1) atomicAdd(&h2[(a >> 13) & (NB2 - 1)], 1u);
  }
  if (t < NB3) h3[t] = 0;
  lgk_barrier();
  unsigned b2;
  find_bin<NB2>(h2, kRem, b2, kRem);
  const unsigned pref2 = (T1 << 7) | b2;        // == a>>13 of threshold

  // P3: among (a>>13)==pref2, bits [12:6] -> h3 ; zero h4.
#pragma unroll
  for (int i = 0; i < VPT; ++i) {
    unsigned a;
    a = v[i].x & 0x7fffffffu; if ((a >> 13) == pref2) atomicAdd(&h3[(a >> 6) & (NB3 - 1)], 1u);
    a = v[i].y & 0x7fffffffu; if ((a >> 13) == pref2) atomicAdd(&h3[(a >> 6) & (NB3 - 1)], 1u);
    a = v[i].z & 0x7fffffffu; if ((a >> 13) == pref2) atomicAdd(&h3[(a >> 6) & (NB3 - 1)], 1u);
    a = v[i].w & 0x7fffffffu; if ((a >> 13) == pref2) atomicAdd(&h3[(a >> 6) & (NB3 - 1)], 1u);
  }
  if (t < NB4) h4[t] = 0;
  lgk_barrier();
  unsigned b3;
  find_bin<NB3>(h3, kRem, b3, kRem);
  const unsigned pref3 = (pref2 << 7) | b3;     // == a>>6 of threshold

  // P4: among (a>>6)==pref3, bits [5:0] -> h4 ; zero h1 (dead since find1).
#pragma unroll
  for (int i = 0; i < VPT; ++i) {
    unsigned a;
    a = v[i].x & 0x7fffffffu; if ((a >> 6) == pref3) atomicAdd(&h4[a & (NB4 - 1)], 1u);
    a = v[i].y & 0x7fffffffu; if ((a >> 6) == pref3) atomicAdd(&h4[a & (NB4 - 1)], 1u);
    a = v[i].z & 0x7fffffffu; if ((a >> 6) == pref3) atomicAdd(&h4[a & (NB4 - 1)], 1u);
    a = v[i].w & 0x7fffffffu; if ((a >> 6) == pref3) atomicAdd(&h4[a & (NB4 - 1)], 1u);
  }
  for (int i = t; i < NB1; i += THREADS) h1[i] = 0;
  lgk_barrier();
  unsigned b4;
  find_bin<NB4>(h4, kRem, b4, kRem);
  const unsigned thr = (pref3 << 6) | b4;       // exact k-th largest |x| bits

  // Masked store (>= keeps ties, same as reference). 16 global stores/thread.
#pragma unroll
  for (int i = 0; i < VPT; ++i) {
    uint4 w = v[i];
    w.x = ((w.x & 0x7fffffffu) >= thr) ? w.x : 0u;
    w.y = ((w.y & 0x7fffffffu) >= thr) ? w.y : 0u;
    w.z = ((w.z & 0x7fffffffu) >= thr) ? w.z : 0u;
    w.w = ((w.w & 0x7fffffffu) >= thr) ? w.w : 0u;
    dstRow[i * THREADS + t] = w;
  }
}

extern "C" __global__ __launch_bounds__(THREADS, 2)
void sparsify_topk_kernel(const float* __restrict__ x, float* __restrict__ out) {
  extern __shared__ __align__(16) unsigned smem[];
  unsigned* data = smem;                 // HW words: DMA landing buffer
  unsigned* h1 = smem + HW;              // NB1
  unsigned* h2 = h1 + NB1;               // NB2
  unsigned* h3 = h2 + NB2;               // NB3
  unsigned* h4 = h3 + NB3;               // NB4
  const uint4* data4 = (const uint4*)data;

  const int t = (int)threadIdx.x;
  const int lane = t & 63, wid = t >> 6;
  const size_t base = (size_t)blockIdx.x * RPB * HW;
  const unsigned* src = (const unsigned*)x + base;
  uint4* dst = (uint4*)out + base / 4;

  // Prologue: zero h1 (h2/h3/h4 get zeroed inside row 0's P1/P2/P3),
  // DMA row 0, drain, copy to regs, issue DMA row 1.
  for (int i = t; i < NB1; i += THREADS) h1[i] = 0;
  dma_row(src, data, wid, lane);
  asm volatile("s_waitcnt vmcnt(0)" ::: "memory");
  lgk_barrier();

  uint4 v[VPT];
#pragma unroll
  for (int i = 0; i < VPT; ++i) v[i] = data4[i * THREADS + t];
  lgk_barrier();                               // all reads done before overwrite
  dma_row(src + HW, data, wid, lane);

  for (int r = 0; r < RPB; ++r) {
    process_row(v, h1, h2, h3, h4, dst + (size_t)r * (HW / 4), t);
    if (r + 1 < RPB) {
      // 16 stores are the only vmem ops younger than the 16 DMA chunks;
      // vmcnt retires in-order, so vmcnt(16) == "this wave's DMA landed".
      asm volatile("s_waitcnt vmcnt(16)" ::: "memory");
      __builtin_amdgcn_s_barrier();            // all waves' chunks landed
#pragma unroll
      for (int i = 0; i < VPT; ++i) v[i] = data4[i * THREADS + t];
      lgk_barrier();                           // reads done before next DMA
      if (r + 2 < RPB) dma_row(src + (size_t)(r + 2) * HW, data, wid, lane);
    }
  }
}

extern "C" void kernel_launch(void* const* d_in, const int* in_sizes, int n_in,
                              void* d_out, int out_size, void* d_ws, size_t ws_size,
                              hipStream_t stream) {
  (void)n_in; (void)d_ws; (void)ws_size; (void)out_size;
  const float* x = (const float*)d_in[0];
  float* out = (float*)d_out;
  const int rows = in_sizes[0] / HW;           // 4096
  const int blocks = rows / RPB;               // 512
  const size_t shmem = (size_t)LDS_WORDS * sizeof(unsigned);  // 75,008 B
  sparsify_topk_kernel<<<dim3(blocks), dim3(THREADS), shmem, stream>>>(x, out);
}